// Round 10
// baseline (7098.066 us; speedup 1.0000x reference)
//
#include <hip/hip_runtime.h>

#define DEVINL __device__ __forceinline__

typedef __bf16 bf16x8 __attribute__((ext_vector_type(8)));
typedef float  f32x4  __attribute__((ext_vector_type(4)));

constexpr int KK = 4096;        // K
constexpr int NN = 11008;       // N
constexpr int NG = 32;          // K / group_size(128)

DEVINL unsigned short f2bf(float f){
  union { float f; unsigned u; } v; v.f = f;
  unsigned r = v.u + 0x7FFF + ((v.u >> 16) & 1);   // RNE; inputs finite here
  return (unsigned short)(r >> 16);
}
DEVINL unsigned pack2(float lo, float hi){
  return (unsigned)f2bf(lo) | ((unsigned)f2bf(hi) << 16);
}
DEVINL void gload16(const void* g, void* l){
  __builtin_amdgcn_global_load_lds(
      (const __attribute__((address_space(1))) void*)g,
      (__attribute__((address_space(3))) void*)l, 16, 0, 0);
}

// ---------------- pre-kernel 1: dequant W (int4-in-int32) -> bf16 [N][K] --
__global__ __launch_bounds__(256) void k_dequant(const int* __restrict__ W,
                                                 const float* __restrict__ S,
                                                 unsigned short* __restrict__ WB){
  int t = blockIdx.x * 256 + threadIdx.x;     // quad id; total NN*(KK/8)
  int row = t >> 9;                           // 512 quads per N-row
  int kp0 = (t & 511) << 2;
  int g   = kp0 >> 6;
  float s = S[row * NG + g];
  const int4 p = reinterpret_cast<const int4*>(W)[t];
  const int* pb = reinterpret_cast<const int*>(&p);
  unsigned q[4];
  #pragma unroll
  for (int i = 0; i < 4; ++i){
    int b = pb[i];
    float lo = ((float)(b & 15)        - 8.0f) * s;
    float hi = ((float)((b >> 4) & 15) - 8.0f) * s;
    q[i] = pack2(lo, hi);
  }
  reinterpret_cast<int4*>(WB)[t] = make_int4((int)q[0], (int)q[1], (int)q[2], (int)q[3]);
}

// ---------------- pre-kernel 2: convert x fp32 -> bf16 [M][K] -------------
__global__ __launch_bounds__(256) void k_cvtA(const float* __restrict__ X,
                                              unsigned short* __restrict__ XB){
  int t = blockIdx.x * 256 + threadIdx.x;
  const float4* src = reinterpret_cast<const float4*>(X) + (size_t)t * 2;
  float4 a = src[0], b = src[1];
  reinterpret_cast<int4*>(XB)[t] = make_int4(
      (int)pack2(a.x, a.y), (int)pack2(a.z, a.w),
      (int)pack2(b.x, b.y), (int)pack2(b.z, b.w));
}

// ============ 256x256 GEMM: 8 waves x 128x64, BK=32, 2 blocks/CU ==========
// R10: per-wave 128x64 output (2.67 MFMA per ds_read_b128 vs R9's 2.0) AND
// 64 KiB LDS (BK=32) so 2 blocks co-reside per CU — one block's barrier /
// staging stall is covered by the other block's MFMA burst. Each wave reads
// exactly ONE A-half and ONE B-half -> R9's verified 1-barrier/tile schedule.
// Swizzle re-derived for 64B rows: byte ^= ((row>>1)&3)<<4 spreads a frag
// read's 16 rows over all 8 (parity,slot) bank groups (2 lanes/bank = free).
constexpr int BM2 = 256, BN2 = 256, BK2 = 32;
constexpr int HBY = 8192;       // half-tile bytes (128 rows x 32 K x bf16)
constexpr int BUFBY = 32768;    // one dbuf buffer (A0,A1,B0,B1)

#define WAIT0  asm volatile("s_waitcnt vmcnt(0)" ::: "memory")
#define BAR()  do { __builtin_amdgcn_s_barrier(); asm volatile("" ::: "memory"); } while (0)

__global__ __launch_bounds__(512, 4) void k_gemm8b(const unsigned short* __restrict__ A,
                                                   const unsigned short* __restrict__ B,
                                                   const float* __restrict__ Bias,
                                                   float* __restrict__ C){
  __shared__ char smem[65536];
  const int tid = threadIdx.x, lane = tid & 63, wid = tid >> 6;   // wid 0..7
  const int wm = wid >> 2, wn = wid & 3;       // 2 x 4 waves
  const int lr = lane & 15, hi = lane >> 4;
  // XCD-aware swizzle: grid = 1376, divisible by 8.
  const int cpx = gridDim.x >> 3;
  const int wg  = (blockIdx.x & 7) * cpx + (blockIdx.x >> 3);
  const int NTT = NN / BN2;                    // 43
  const int mt = wg / NTT, nt = wg % NTT;
  const char* Ab = (const char*)(A + (size_t)mt * BM2 * KK);
  const char* Bb = (const char*)(B + (size_t)nt * BN2 * KK);
  const int srow  = tid >> 2;                  // staging row (0..127)
  const int scolb = (tid & 3) * 16;            // staging col byte (0..48)

  // Stage one half (sel: 0=A rows0-127, 1=A rows128-255, 2=B cols0-127,
  // 3=B cols128-255) of K-tile kt into buf: one gload16 per thread.
  auto stage_half = [&](int buf, int sel, int kt){
    const char* base = ((sel >= 2) ? Bb : Ab) + (size_t)((sel & 1) * 128) * KK * 2;
    const char* src = base + (size_t)srow * (KK * 2) + kt * (BK2 * 2)
                    + (scolb ^ (((srow >> 1) & 3) << 4));    // inverse-swizzled src
    char* dst = smem + buf * BUFBY + sel * HBY + tid * 16;   // linear dst
    gload16(src, dst);
  };
  // Swizzled LDS fragment read (16B); row stride 64B.
  auto frag = [&](int buf, int sel, int row, int bcol) -> bf16x8 {
    return *reinterpret_cast<const bf16x8*>(
        smem + buf * BUFBY + sel * HBY + row * 64 + (bcol ^ (((row >> 1) & 3) << 4)));
  };

  const int selA = wm;                         // this wave's A-half (128 rows)
  const int selB = 2 + (wn >> 1);              // this wave's B-half
  const int cB0  = (wn & 1) * 64;              // col base within B-half

  f32x4 acc[8][4] = {};

  // Prologue: stage all 4 halves of K-tile 0, drain, barrier.
  stage_half(0, 0, 0); stage_half(0, 1, 0);
  stage_half(0, 2, 0); stage_half(0, 3, 0);
  WAIT0;
  BAR();

  const int NT = KK / BK2;                     // 128 K-tiles
  for (int t = 0; t < NT; ++t){
    const int buf = t & 1;
    const bool pf = (t + 1 < NT);
    if (pf){                                   // issue next-tile stages first
      stage_half(buf ^ 1, 0, t + 1);
      stage_half(buf ^ 1, 1, t + 1);
      stage_half(buf ^ 1, 2, t + 1);
      stage_half(buf ^ 1, 3, t + 1);
    }
    bf16x8 af[8], bf[4];
    #pragma unroll
    for (int i = 0; i < 8; ++i)
      af[i] = frag(buf, selA, i*16 + lr, hi*16);
    #pragma unroll
    for (int j = 0; j < 4; ++j)
      bf[j] = frag(buf, selB, cB0 + j*16 + lr, hi*16);
    __builtin_amdgcn_s_setprio(1);
    #pragma unroll
    for (int i = 0; i < 8; ++i)
      #pragma unroll
      for (int j = 0; j < 4; ++j)
        acc[i][j] = __builtin_amdgcn_mfma_f32_16x16x32_bf16(af[i], bf[j], acc[i][j], 0, 0, 0);
    __builtin_amdgcn_s_setprio(0);
    if (pf) WAIT0;                             // own stages landed (issued ~1 tile ago)
    BAR();                                     // global: staged data visible, reads done
  }

  // Epilogue: bias + fp32 store. row = cmb + wm*128 + i*16 + hi*4 + r;
  // col = cnb + wn*64 + j*16 + lr.
  const int cmb = mt * BM2, cnb = nt * BN2;
  #pragma unroll
  for (int j = 0; j < 4; ++j){
    int col = cnb + wn * 64 + j * 16 + lr;
    float bv = Bias[col];
    #pragma unroll
    for (int i = 0; i < 8; ++i){
      int row0 = cmb + wm * 128 + i * 16 + hi * 4;
      #pragma unroll
      for (int r = 0; r < 4; ++r)
        C[(size_t)(row0 + r) * NN + col] = acc[i][j][r] + bv;
    }
  }
}

// ---------------- fallback (verified round 3): A fp32, reg-staged ---------
constexpr int BM = 128, BN = 128, BK = 32;
__global__ __launch_bounds__(256) void k_gemm_ws(const float* __restrict__ A,
                                                 const unsigned short* __restrict__ B,
                                                 const float* __restrict__ Bias,
                                                 float* __restrict__ C){
  __shared__ unsigned short As[2][BM][BK];
  __shared__ unsigned short Bs[2][BN][BK];
  const int tid = threadIdx.x;
  const int NT = NN / BN;
  const int mt = blockIdx.x / NT, nt = blockIdx.x % NT;
  const float*          Ab = A + (size_t)mt * BM * KK;
  const unsigned short* Bb = B + (size_t)nt * BN * KK;
  const int lane = tid & 63, wid = tid >> 6;
  const int wm = wid >> 1, wn = wid & 1;
  const int lr = lane & 15, lk = (lane >> 4) << 3;

  auto ld = [&](int kt, float4* ra, int4* rb){
    #pragma unroll
    for (int r = 0; r < 2; ++r){
      int c = r * 256 + tid, row = c >> 2, k0 = (c & 3) << 3;
      const float* src = Ab + (size_t)row * KK + kt * BK + k0;
      ra[2*r]   = *reinterpret_cast<const float4*>(src);
      ra[2*r+1] = *reinterpret_cast<const float4*>(src + 4);
      rb[r] = *reinterpret_cast<const int4*>(Bb + (size_t)row * KK + kt * BK + k0);
    }
  };
  auto st = [&](int buf, const float4* ra, const int4* rb){
    #pragma unroll
    for (int r = 0; r < 2; ++r){
      int c = r * 256 + tid, row = c >> 2, k0 = (c & 3) << 3;
      unsigned q[4];
      #pragma unroll
      for (int i = 0; i < 4; ++i)
        q[i] = pack2(ra[2*r + (i >> 1)][(i & 1) * 2], ra[2*r + (i >> 1)][(i & 1) * 2 + 1]);
      *reinterpret_cast<int4*>(&As[buf][row][k0]) =
          make_int4((int)q[0], (int)q[1], (int)q[2], (int)q[3]);
      *reinterpret_cast<int4*>(&Bs[buf][row][k0]) = rb[r];
    }
  };

  f32x4 acc[4][4] = {};
  {
    float4 ra[4]; int4 rb[2];
    ld(0, ra, rb);
    st(0, ra, rb);
  }
  __syncthreads();
  const int KT = KK / BK;
  for (int kt = 0; kt < KT; ++kt){
    int cur = kt & 1;
    float4 na[4]; int4 nb[2];
    if (kt + 1 < KT) ld(kt + 1, na, nb);
    bf16x8 af[4], bfr[4];
    #pragma unroll
    for (int i = 0; i < 4; ++i)
      af[i] = *reinterpret_cast<const bf16x8*>(&As[cur][wm*64 + i*16 + lr][lk]);
    #pragma unroll
    for (int i = 0; i < 4; ++i)
      bfr[i] = *reinterpret_cast<const bf16x8*>(&Bs[cur][wn*64 + i*16 + lr][lk]);
    #pragma unroll
    for (int i = 0; i < 4; ++i)
      #pragma unroll
      for (int j = 0; j < 4; ++j)
        acc[i][j] = __builtin_amdgcn_mfma_f32_16x16x32_bf16(af[i], bfr[j], acc[i][j], 0, 0, 0);
    if (kt + 1 < KT) st(cur ^ 1, na, nb);
    __syncthreads();
  }
  const int cm = mt * BM + wm * 64;
  const int cn = nt * BN + wn * 64;
  float bv[4];
  #pragma unroll
  for (int j = 0; j < 4; ++j) bv[j] = Bias[cn + j*16 + lr];
  #pragma unroll
  for (int i = 0; i < 4; ++i)
    #pragma unroll
    for (int j = 0; j < 4; ++j)
      #pragma unroll
      for (int r = 0; r < 4; ++r){
        size_t rr = (size_t)(cm + i*16 + (lane >> 4)*4 + r);
        C[rr * NN + (cn + j*16 + lr)] = acc[i][j][r] + bv[j];
      }
}

extern "C" void kernel_launch(void* const* d_in, const int* in_sizes, int n_in,
                              void* d_out, int out_size, void* d_ws, size_t ws_size,
                              hipStream_t stream){
  const float* x    = (const float*)d_in[0];   // fp32 [M][K] (fp16 ref -> float)
  const int*   w    = (const int*)d_in[1];     // [N][K/2] packed bytes
  const float* s    = (const float*)d_in[2];   // fp32 [N][NG]
  const float* bias = (const float*)d_in[3];   // fp32 [N]
  float* out = (float*)d_out;                  // fp32 [M][N]
  const int M = in_sizes[0] / KK;              // 8192
  const size_t needW = (size_t)NN * KK * 2;    // 90.2 MB for bf16 W
  const size_t needA = (size_t)M * KK * 2;     // 67.1 MB for bf16 x
  const int dq_blocks = (NN * (KK / 8)) / 256;

  if (ws_size >= needW + needA && (M % BM2) == 0){
    unsigned short* wb = (unsigned short*)d_ws;
    unsigned short* xb = (unsigned short*)((char*)d_ws + needW);
    k_dequant<<<dq_blocks, 256, 0, stream>>>(w, s, wb);
    k_cvtA<<<(M * (KK / 8)) / 256, 256, 0, stream>>>(x, xb);
    const int grid8 = (M / BM2) * (NN / BN2);      // 32*43 = 1376
    k_gemm8b<<<grid8, 512, 0, stream>>>(xb, wb, bias, out);
  } else {
    unsigned short* wb = (unsigned short*)d_ws;
    k_dequant<<<dq_blocks, 256, 0, stream>>>(w, s, wb);
    const int grid = (M / BM) * (NN / BN);
    k_gemm_ws<<<grid, 256, 0, stream>>>(x, wb, bias, out);
  }
}

// Round 11
// 989.077 us; speedup vs baseline: 7.1765x; 7.1765x over previous
//
#include <hip/hip_runtime.h>

#define DEVINL __device__ __forceinline__

typedef __bf16 bf16x8 __attribute__((ext_vector_type(8)));
typedef float  f32x4  __attribute__((ext_vector_type(4)));

constexpr int KK = 4096;        // K
constexpr int NN = 11008;       // N
constexpr int NG = 32;          // K / group_size(128)

DEVINL unsigned short f2bf(float f){
  union { float f; unsigned u; } v; v.f = f;
  unsigned r = v.u + 0x7FFF + ((v.u >> 16) & 1);   // RNE; inputs finite here
  return (unsigned short)(r >> 16);
}
DEVINL unsigned pack2(float lo, float hi){
  return (unsigned)f2bf(lo) | ((unsigned)f2bf(hi) << 16);
}
DEVINL void gload16(const void* g, void* l){
  __builtin_amdgcn_global_load_lds(
      (const __attribute__((address_space(1))) void*)g,
      (__attribute__((address_space(3))) void*)l, 16, 0, 0);
}

// ---------------- pre-kernel 1: dequant W (int4-in-int32) -> bf16 [N][K] --
__global__ __launch_bounds__(256) void k_dequant(const int* __restrict__ W,
                                                 const float* __restrict__ S,
                                                 unsigned short* __restrict__ WB){
  int t = blockIdx.x * 256 + threadIdx.x;     // quad id; total NN*(KK/8)
  int row = t >> 9;                           // 512 quads per N-row
  int kp0 = (t & 511) << 2;
  int g   = kp0 >> 6;
  float s = S[row * NG + g];
  const int4 p = reinterpret_cast<const int4*>(W)[t];
  const int* pb = reinterpret_cast<const int*>(&p);
  unsigned q[4];
  #pragma unroll
  for (int i = 0; i < 4; ++i){
    int b = pb[i];
    float lo = ((float)(b & 15)        - 8.0f) * s;
    float hi = ((float)((b >> 4) & 15) - 8.0f) * s;
    q[i] = pack2(lo, hi);
  }
  reinterpret_cast<int4*>(WB)[t] = make_int4((int)q[0], (int)q[1], (int)q[2], (int)q[3]);
}

// ---------------- pre-kernel 2: convert x fp32 -> bf16 [M][K] -------------
__global__ __launch_bounds__(256) void k_cvtA(const float* __restrict__ X,
                                              unsigned short* __restrict__ XB){
  int t = blockIdx.x * 256 + threadIdx.x;
  const float4* src = reinterpret_cast<const float4*>(X) + (size_t)t * 2;
  float4 a = src[0], b = src[1];
  reinterpret_cast<int4*>(XB)[t] = make_int4(
      (int)pack2(a.x, a.y), (int)pack2(a.z, a.w),
      (int)pack2(b.x, b.y), (int)pack2(b.z, b.w));
}

// ====== 128x256 GEMM: 4 waves x 64x128, BK=32, 2 blocks/CU (R11) ==========
// R10's spill root-cause: 128x64/wave acc(128 AGPR) cannot coexist with a
// 128-reg/wave cap (16 waves/CU). R11 keeps the high MFMA/ds_read ratio
// (2.67) but at 8 waves/CU (256-reg cap, no spill): 256-thr blocks, 2
// independent barrier groups per CU so one block's stage/barrier stall is
// covered by the other's MFMA burst (R8/R9 were single-barrier-group).
// Schedule = R9's verified 1-barrier/tile. Swizzle = R10's 64B-row form
// (verified correct): byte ^= ((row>>1)&3)<<4, inverse-applied on global src.
constexpr int BM2 = 128, BN2 = 256, BK2 = 32;
constexpr int ABY = 8192;       // A panel bytes (128 x 32 x bf16)
constexpr int BBY = 16384;      // B panel bytes (256 x 32 x bf16)
constexpr int BUFBY = 24576;    // one dbuf buffer (A + B)

#define WAIT0  asm volatile("s_waitcnt vmcnt(0)" ::: "memory")
#define BAR()  do { __builtin_amdgcn_s_barrier(); asm volatile("" ::: "memory"); } while (0)

__global__ __launch_bounds__(256, 2) void k_gemm4w(const unsigned short* __restrict__ A,
                                                   const unsigned short* __restrict__ B,
                                                   const float* __restrict__ Bias,
                                                   float* __restrict__ C){
  __shared__ char smem[49152];
  const int tid = threadIdx.x, lane = tid & 63, wid = tid >> 6;   // wid 0..3
  const int wm = wid >> 1, wn = wid & 1;       // 2 x 2 waves
  const int lr = lane & 15, hi = lane >> 4;
  // XCD-aware swizzle: grid = 2752, divisible by 8.
  const int cpx = gridDim.x >> 3;
  const int wg  = (blockIdx.x & 7) * cpx + (blockIdx.x >> 3);
  const int NTT = NN / BN2;                    // 43
  const int mt = wg / NTT, nt = wg % NTT;
  const char* Ab = (const char*)(A + (size_t)mt * BM2 * KK);
  const char* Bb = (const char*)(B + (size_t)nt * BN2 * KK);
  const int srow  = tid >> 2;                  // staging row within pass (0..63)
  const int scolb = (tid & 3) * 16;            // staging col byte (0..48)

  // Stage tile kt into buf: A = 2 passes of 64 rows, B = 4 passes. 6 gloads.
  auto stage = [&](int buf, int kt){
    #pragma unroll
    for (int p = 0; p < 2; ++p){               // A rows p*64 + srow
      int row = p * 64 + srow;
      const char* src = Ab + (size_t)row * (KK * 2) + kt * (BK2 * 2)
                      + (scolb ^ (((row >> 1) & 3) << 4));
      gload16(src, smem + buf * BUFBY + p * 4096 + tid * 16);
    }
    #pragma unroll
    for (int p = 0; p < 4; ++p){               // B rows p*64 + srow
      int row = p * 64 + srow;
      const char* src = Bb + (size_t)row * (KK * 2) + kt * (BK2 * 2)
                      + (scolb ^ (((row >> 1) & 3) << 4));
      gload16(src, smem + buf * BUFBY + ABY + p * 4096 + tid * 16);
    }
  };
  // Swizzled LDS fragment read (16B); row stride 64B. isB: 0=A, 1=B panel.
  auto frag = [&](int buf, int isB, int row) -> bf16x8 {
    return *reinterpret_cast<const bf16x8*>(
        smem + buf * BUFBY + isB * ABY + row * 64
             + ((hi * 16) ^ (((row >> 1) & 3) << 4)));
  };

  f32x4 acc[4][8] = {};

  // Prologue: stage K-tile 0, drain, barrier.
  stage(0, 0);
  WAIT0;
  BAR();

  const int NT = KK / BK2;                     // 128 K-tiles
  for (int t = 0; t < NT; ++t){
    const int buf = t & 1;
    const bool pf = (t + 1 < NT);
    if (pf) stage(buf ^ 1, t + 1);             // 6 gloads issued first
    bf16x8 af[4], bf[8];
    #pragma unroll
    for (int i = 0; i < 4; ++i)
      af[i] = frag(buf, 0, wm*64 + i*16 + lr);
    #pragma unroll
    for (int j = 0; j < 8; ++j)
      bf[j] = frag(buf, 1, wn*128 + j*16 + lr);
    __builtin_amdgcn_s_setprio(1);
    #pragma unroll
    for (int i = 0; i < 4; ++i)
      #pragma unroll
      for (int j = 0; j < 8; ++j)
        acc[i][j] = __builtin_amdgcn_mfma_f32_16x16x32_bf16(af[i], bf[j], acc[i][j], 0, 0, 0);
    __builtin_amdgcn_s_setprio(0);
    if (pf) WAIT0;                             // own 6 stages landed
    BAR();                                     // global: staged visible, reads done
  }

  // Epilogue: bias + fp32 store. row = cmb + wm*64 + i*16 + hi*4 + r;
  // col = cnb + wn*128 + j*16 + lr.
  const int cmb = mt * BM2, cnb = nt * BN2;
  #pragma unroll
  for (int j = 0; j < 8; ++j){
    int col = cnb + wn * 128 + j * 16 + lr;
    float bv = Bias[col];
    #pragma unroll
    for (int i = 0; i < 4; ++i){
      int row0 = cmb + wm * 64 + i * 16 + hi * 4;
      #pragma unroll
      for (int r = 0; r < 4; ++r)
        C[(size_t)(row0 + r) * NN + col] = acc[i][j][r] + bv;
    }
  }
}

// ---------------- fallback (verified round 3): A fp32, reg-staged ---------
constexpr int BM = 128, BN = 128, BK = 32;
__global__ __launch_bounds__(256) void k_gemm_ws(const float* __restrict__ A,
                                                 const unsigned short* __restrict__ B,
                                                 const float* __restrict__ Bias,
                                                 float* __restrict__ C){
  __shared__ unsigned short As[2][BM][BK];
  __shared__ unsigned short Bs[2][BN][BK];
  const int tid = threadIdx.x;
  const int NT = NN / BN;
  const int mt = blockIdx.x / NT, nt = blockIdx.x % NT;
  const float*          Ab = A + (size_t)mt * BM * KK;
  const unsigned short* Bb = B + (size_t)nt * BN * KK;
  const int lane = tid & 63, wid = tid >> 6;
  const int wm = wid >> 1, wn = wid & 1;
  const int lr = lane & 15, lk = (lane >> 4) << 3;

  auto ld = [&](int kt, float4* ra, int4* rb){
    #pragma unroll
    for (int r = 0; r < 2; ++r){
      int c = r * 256 + tid, row = c >> 2, k0 = (c & 3) << 3;
      const float* src = Ab + (size_t)row * KK + kt * BK + k0;
      ra[2*r]   = *reinterpret_cast<const float4*>(src);
      ra[2*r+1] = *reinterpret_cast<const float4*>(src + 4);
      rb[r] = *reinterpret_cast<const int4*>(Bb + (size_t)row * KK + kt * BK + k0);
    }
  };
  auto st = [&](int buf, const float4* ra, const int4* rb){
    #pragma unroll
    for (int r = 0; r < 2; ++r){
      int c = r * 256 + tid, row = c >> 2, k0 = (c & 3) << 3;
      unsigned q[4];
      #pragma unroll
      for (int i = 0; i < 4; ++i)
        q[i] = pack2(ra[2*r + (i >> 1)][(i & 1) * 2], ra[2*r + (i >> 1)][(i & 1) * 2 + 1]);
      *reinterpret_cast<int4*>(&As[buf][row][k0]) =
          make_int4((int)q[0], (int)q[1], (int)q[2], (int)q[3]);
      *reinterpret_cast<int4*>(&Bs[buf][row][k0]) = rb[r];
    }
  };

  f32x4 acc[4][4] = {};
  {
    float4 ra[4]; int4 rb[2];
    ld(0, ra, rb);
    st(0, ra, rb);
  }
  __syncthreads();
  const int KT = KK / BK;
  for (int kt = 0; kt < KT; ++kt){
    int cur = kt & 1;
    float4 na[4]; int4 nb[2];
    if (kt + 1 < KT) ld(kt + 1, na, nb);
    bf16x8 af[4], bfr[4];
    #pragma unroll
    for (int i = 0; i < 4; ++i)
      af[i] = *reinterpret_cast<const bf16x8*>(&As[cur][wm*64 + i*16 + lr][lk]);
    #pragma unroll
    for (int i = 0; i < 4; ++i)
      bfr[i] = *reinterpret_cast<const bf16x8*>(&Bs[cur][wn*64 + i*16 + lr][lk]);
    #pragma unroll
    for (int i = 0; i < 4; ++i)
      #pragma unroll
      for (int j = 0; j < 4; ++j)
        acc[i][j] = __builtin_amdgcn_mfma_f32_16x16x32_bf16(af[i], bfr[j], acc[i][j], 0, 0, 0);
    if (kt + 1 < KT) st(cur ^ 1, na, nb);
    __syncthreads();
  }
  const int cm = mt * BM + wm * 64;
  const int cn = nt * BN + wn * 64;
  float bv[4];
  #pragma unroll
  for (int j = 0; j < 4; ++j) bv[j] = Bias[cn + j*16 + lr];
  #pragma unroll
  for (int i = 0; i < 4; ++i)
    #pragma unroll
    for (int j = 0; j < 4; ++j)
      #pragma unroll
      for (int r = 0; r < 4; ++r){
        size_t rr = (size_t)(cm + i*16 + (lane >> 4)*4 + r);
        C[rr * NN + (cn + j*16 + lr)] = acc[i][j][r] + bv[j];
      }
}

extern "C" void kernel_launch(void* const* d_in, const int* in_sizes, int n_in,
                              void* d_out, int out_size, void* d_ws, size_t ws_size,
                              hipStream_t stream){
  const float* x    = (const float*)d_in[0];   // fp32 [M][K] (fp16 ref -> float)
  const int*   w    = (const int*)d_in[1];     // [N][K/2] packed bytes
  const float* s    = (const float*)d_in[2];   // fp32 [N][NG]
  const float* bias = (const float*)d_in[3];   // fp32 [N]
  float* out = (float*)d_out;                  // fp32 [M][N]
  const int M = in_sizes[0] / KK;              // 8192
  const size_t needW = (size_t)NN * KK * 2;    // 90.2 MB for bf16 W
  const size_t needA = (size_t)M * KK * 2;     // 67.1 MB for bf16 x
  const int dq_blocks = (NN * (KK / 8)) / 256;

  if (ws_size >= needW + needA && (M % BM2) == 0){
    unsigned short* wb = (unsigned short*)d_ws;
    unsigned short* xb = (unsigned short*)((char*)d_ws + needW);
    k_dequant<<<dq_blocks, 256, 0, stream>>>(w, s, wb);
    k_cvtA<<<(M * (KK / 8)) / 256, 256, 0, stream>>>(x, xb);
    const int grid4 = (M / BM2) * (NN / BN2);      // 64*43 = 2752
    k_gemm4w<<<grid4, 256, 0, stream>>>(xb, wb, bias, out);
  } else {
    unsigned short* wb = (unsigned short*)d_ws;
    k_dequant<<<dq_blocks, 256, 0, stream>>>(w, s, wb);
    const int grid = (M / BM) * (NN / BN);
    k_gemm_ws<<<grid, 256, 0, stream>>>(x, wb, bias, out);
  }
}

// Round 12
// 768.612 us; speedup vs baseline: 9.2349x; 1.2868x over previous
//
#include <hip/hip_runtime.h>

#define DEVINL __device__ __forceinline__

typedef __bf16 bf16x8 __attribute__((ext_vector_type(8)));
typedef float  f32x4  __attribute__((ext_vector_type(4)));

constexpr int KK = 4096;        // K
constexpr int NN = 11008;       // N
constexpr int NG = 32;          // K / group_size(128)

DEVINL unsigned short f2bf(float f){
  union { float f; unsigned u; } v; v.f = f;
  unsigned r = v.u + 0x7FFF + ((v.u >> 16) & 1);   // RNE; inputs finite here
  return (unsigned short)(r >> 16);
}
DEVINL unsigned pack2(float lo, float hi){
  return (unsigned)f2bf(lo) | ((unsigned)f2bf(hi) << 16);
}
DEVINL void gload16(const void* g, void* l){
  __builtin_amdgcn_global_load_lds(
      (const __attribute__((address_space(1))) void*)g,
      (__attribute__((address_space(3))) void*)l, 16, 0, 0);
}

// ---------------- pre-kernel 1: dequant W (int4-in-int32) -> bf16 [N][K] --
__global__ __launch_bounds__(256) void k_dequant(const int* __restrict__ W,
                                                 const float* __restrict__ S,
                                                 unsigned short* __restrict__ WB){
  int t = blockIdx.x * 256 + threadIdx.x;     // quad id; total NN*(KK/8)
  int row = t >> 9;                           // 512 quads per N-row
  int kp0 = (t & 511) << 2;
  int g   = kp0 >> 6;
  float s = S[row * NG + g];
  const int4 p = reinterpret_cast<const int4*>(W)[t];
  const int* pb = reinterpret_cast<const int*>(&p);
  unsigned q[4];
  #pragma unroll
  for (int i = 0; i < 4; ++i){
    int b = pb[i];
    float lo = ((float)(b & 15)        - 8.0f) * s;
    float hi = ((float)((b >> 4) & 15) - 8.0f) * s;
    q[i] = pack2(lo, hi);
  }
  reinterpret_cast<int4*>(WB)[t] = make_int4((int)q[0], (int)q[1], (int)q[2], (int)q[3]);
}

// ---------------- pre-kernel 2: convert x fp32 -> bf16 [M][K] -------------
__global__ __launch_bounds__(256) void k_cvtA(const float* __restrict__ X,
                                              unsigned short* __restrict__ XB){
  int t = blockIdx.x * 256 + threadIdx.x;
  const float4* src = reinterpret_cast<const float4*>(X) + (size_t)t * 2;
  float4 a = src[0], b = src[1];
  reinterpret_cast<int4*>(XB)[t] = make_int4(
      (int)pack2(a.x, a.y), (int)pack2(a.z, a.w),
      (int)pack2(b.x, b.y), (int)pack2(b.z, b.w));
}

// ====== 256x256 GEMM: 8 waves x 128x64, BK=64, 1 barrier/K-tile (R12) =====
// Recombines the verified pieces: 256^2 tile (R9: lowest HBM refetch, 1.5GB),
// R8's wave shape (128x64/wave = 2.67 MFMA per ds_read_b128, 192 reads/CU/
// tile vs R9's 256), R9's schedule (each wave reads ONE A-half + ONE B-half
// -> stage-early, 1 WAIT0 + 1 barrier per tile, no quadrant phases).
// Registers: acc 128 + ks-split frags 48 + addr ~25 at 8 waves/CU (512,1).
// R10's spill came from demanding 16 waves/CU on this datapath — not done here.
constexpr int BM2 = 256, BN2 = 256, BK2 = 64;
constexpr int HBY = 16384;      // half-tile bytes (128 rows x 64 K x bf16)
constexpr int BUFBY = 65536;    // one dbuf buffer (A0,A1,B0,B1)

#define WAIT0  asm volatile("s_waitcnt vmcnt(0)" ::: "memory")
#define BAR()  do { __builtin_amdgcn_s_barrier(); asm volatile("" ::: "memory"); } while (0)

__global__ __launch_bounds__(512, 1) void k_gemm8c(const unsigned short* __restrict__ A,
                                                   const unsigned short* __restrict__ B,
                                                   const float* __restrict__ Bias,
                                                   float* __restrict__ C){
  __shared__ char smem[131072];
  const int tid = threadIdx.x, lane = tid & 63, wid = tid >> 6;   // wid 0..7
  const int wm = wid >> 2, wn = wid & 3;       // 2 x 4 waves
  const int lr = lane & 15, hi = lane >> 4;
  // XCD-aware swizzle: grid = 1376, divisible by 8.
  const int cpx = gridDim.x >> 3;
  const int wg  = (blockIdx.x & 7) * cpx + (blockIdx.x >> 3);
  const int NTT = NN / BN2;                    // 43
  const int mt = wg / NTT, nt = wg % NTT;
  const char* Ab = (const char*)(A + (size_t)mt * BM2 * KK);
  const char* Bb = (const char*)(B + (size_t)nt * BN2 * KK);
  const int srow  = tid >> 3;                  // staging row (0..63, x2 passes)
  const int scolb = (tid & 7) * 16;            // staging col byte (0..112)

  // Stage one half (sel: 0=A rows0-127, 1=A rows128-255, 2=B cols0-127,
  // 3=B cols128-255) of K-tile kt into buf: 2 gload16 per thread.
  auto stage_half = [&](int buf, int sel, int kt){
    const char* base = ((sel >= 2) ? Bb : Ab) + (size_t)((sel & 1) * 128) * KK * 2;
    #pragma unroll
    for (int r = 0; r < 2; ++r){
      int row = r * 64 + srow;
      const char* src = base + (size_t)row * (KK * 2) + kt * (BK2 * 2)
                      + (scolb ^ ((row & 7) << 4));          // inverse-swizzled src
      char* dst = smem + buf * BUFBY + sel * HBY + r * 8192 + tid * 16;  // linear dst
      gload16(src, dst);
    }
  };
  // Swizzled LDS fragment read (16B); row stride 128B. (Verified R5-R9.)
  auto frag = [&](int buf, int sel, int row, int bcol) -> bf16x8 {
    return *reinterpret_cast<const bf16x8*>(
        smem + buf * BUFBY + sel * HBY + row * 128 + (bcol ^ ((row & 7) << 4)));
  };

  const int selA = wm;                         // this wave's A-half (128 rows)
  const int selB = 2 + (wn >> 1);              // this wave's B-half
  const int cB0  = (wn & 1) * 64;              // col base within B-half

  f32x4 acc[8][4] = {};

  // Prologue: stage all 4 halves of K-tile 0, drain, barrier.
  stage_half(0, 0, 0); stage_half(0, 1, 0);
  stage_half(0, 2, 0); stage_half(0, 3, 0);
  WAIT0;
  BAR();

  const int NT = KK / BK2;                     // 64 K-tiles
  for (int t = 0; t < NT; ++t){
    const int buf = t & 1;
    const bool pf = (t + 1 < NT);
    if (pf){                                   // issue next-tile stages first:
      stage_half(buf ^ 1, 0, t + 1);           // 8 gloads in flight across the
      stage_half(buf ^ 1, 1, t + 1);           // whole tile body (~2500 cyc)
      stage_half(buf ^ 1, 2, t + 1);           // -> HBM/L2 latency covered.
      stage_half(buf ^ 1, 3, t + 1);
    }
    #pragma unroll
    for (int ks = 0; ks < 2; ++ks){            // ks-split: 48 live frag VGPRs
      bf16x8 af[8], bf[4];
      #pragma unroll
      for (int i = 0; i < 8; ++i)
        af[i] = frag(buf, selA, i*16 + lr, ks*64 + hi*16);
      #pragma unroll
      for (int j = 0; j < 4; ++j)
        bf[j] = frag(buf, selB, cB0 + j*16 + lr, ks*64 + hi*16);
      __builtin_amdgcn_s_setprio(1);
      #pragma unroll
      for (int i = 0; i < 8; ++i)
        #pragma unroll
        for (int j = 0; j < 4; ++j)
          acc[i][j] = __builtin_amdgcn_mfma_f32_16x16x32_bf16(af[i], bf[j], acc[i][j], 0, 0, 0);
      __builtin_amdgcn_s_setprio(0);
    }
    if (pf) WAIT0;                             // own 8 stages landed (issued ~1 tile ago)
    BAR();                                     // global: staged visible, reads of buf done
  }

  // Epilogue: bias + fp32 store. row = cmb + wm*128 + i*16 + hi*4 + r;
  // col = cnb + wn*64 + j*16 + lr.
  const int cmb = mt * BM2, cnb = nt * BN2;
  #pragma unroll
  for (int j = 0; j < 4; ++j){
    int col = cnb + wn * 64 + j * 16 + lr;
    float bv = Bias[col];
    #pragma unroll
    for (int i = 0; i < 8; ++i){
      int row0 = cmb + wm * 128 + i * 16 + hi * 4;
      #pragma unroll
      for (int r = 0; r < 4; ++r)
        C[(size_t)(row0 + r) * NN + col] = acc[i][j][r] + bv;
    }
  }
}

// ---------------- fallback (verified round 3): A fp32, reg-staged ---------
constexpr int BM = 128, BN = 128, BK = 32;
__global__ __launch_bounds__(256) void k_gemm_ws(const float* __restrict__ A,
                                                 const unsigned short* __restrict__ B,
                                                 const float* __restrict__ Bias,
                                                 float* __restrict__ C){
  __shared__ unsigned short As[2][BM][BK];
  __shared__ unsigned short Bs[2][BN][BK];
  const int tid = threadIdx.x;
  const int NT = NN / BN;
  const int mt = blockIdx.x / NT, nt = blockIdx.x % NT;
  const float*          Ab = A + (size_t)mt * BM * KK;
  const unsigned short* Bb = B + (size_t)nt * BN * KK;
  const int lane = tid & 63, wid = tid >> 6;
  const int wm = wid >> 1, wn = wid & 1;
  const int lr = lane & 15, lk = (lane >> 4) << 3;

  auto ld = [&](int kt, float4* ra, int4* rb){
    #pragma unroll
    for (int r = 0; r < 2; ++r){
      int c = r * 256 + tid, row = c >> 2, k0 = (c & 3) << 3;
      const float* src = Ab + (size_t)row * KK + kt * BK + k0;
      ra[2*r]   = *reinterpret_cast<const float4*>(src);
      ra[2*r+1] = *reinterpret_cast<const float4*>(src + 4);
      rb[r] = *reinterpret_cast<const int4*>(Bb + (size_t)row * KK + kt * BK + k0);
    }
  };
  auto st = [&](int buf, const float4* ra, const int4* rb){
    #pragma unroll
    for (int r = 0; r < 2; ++r){
      int c = r * 256 + tid, row = c >> 2, k0 = (c & 3) << 3;
      unsigned q[4];
      #pragma unroll
      for (int i = 0; i < 4; ++i)
        q[i] = pack2(ra[2*r + (i >> 1)][(i & 1) * 2], ra[2*r + (i >> 1)][(i & 1) * 2 + 1]);
      *reinterpret_cast<int4*>(&As[buf][row][k0]) =
          make_int4((int)q[0], (int)q[1], (int)q[2], (int)q[3]);
      *reinterpret_cast<int4*>(&Bs[buf][row][k0]) = rb[r];
    }
  };

  f32x4 acc[4][4] = {};
  {
    float4 ra[4]; int4 rb[2];
    ld(0, ra, rb);
    st(0, ra, rb);
  }
  __syncthreads();
  const int KT = KK / BK;
  for (int kt = 0; kt < KT; ++kt){
    int cur = kt & 1;
    float4 na[4]; int4 nb[2];
    if (kt + 1 < KT) ld(kt + 1, na, nb);
    bf16x8 af[4], bfr[4];
    #pragma unroll
    for (int i = 0; i < 4; ++i)
      af[i] = *reinterpret_cast<const bf16x8*>(&As[cur][wm*64 + i*16 + lr][lk]);
    #pragma unroll
    for (int i = 0; i < 4; ++i)
      bfr[i] = *reinterpret_cast<const bf16x8*>(&Bs[cur][wn*64 + i*16 + lr][lk]);
    #pragma unroll
    for (int i = 0; i < 4; ++i)
      #pragma unroll
      for (int j = 0; j < 4; ++j)
        acc[i][j] = __builtin_amdgcn_mfma_f32_16x16x32_bf16(af[i], bfr[j], acc[i][j], 0, 0, 0);
    if (kt + 1 < KT) st(cur ^ 1, na, nb);
    __syncthreads();
  }
  const int cm = mt * BM + wm * 64;
  const int cn = nt * BN + wn * 64;
  float bv[4];
  #pragma unroll
  for (int j = 0; j < 4; ++j) bv[j] = Bias[cn + j*16 + lr];
  #pragma unroll
  for (int i = 0; i < 4; ++i)
    #pragma unroll
    for (int j = 0; j < 4; ++j)
      #pragma unroll
      for (int r = 0; r < 4; ++r){
        size_t rr = (size_t)(cm + i*16 + (lane >> 4)*4 + r);
        C[rr * NN + (cn + j*16 + lr)] = acc[i][j][r] + bv[j];
      }
}

extern "C" void kernel_launch(void* const* d_in, const int* in_sizes, int n_in,
                              void* d_out, int out_size, void* d_ws, size_t ws_size,
                              hipStream_t stream){
  const float* x    = (const float*)d_in[0];   // fp32 [M][K] (fp16 ref -> float)
  const int*   w    = (const int*)d_in[1];     // [N][K/2] packed bytes
  const float* s    = (const float*)d_in[2];   // fp32 [N][NG]
  const float* bias = (const float*)d_in[3];   // fp32 [N]
  float* out = (float*)d_out;                  // fp32 [M][N]
  const int M = in_sizes[0] / KK;              // 8192
  const size_t needW = (size_t)NN * KK * 2;    // 90.2 MB for bf16 W
  const size_t needA = (size_t)M * KK * 2;     // 67.1 MB for bf16 x
  const int dq_blocks = (NN * (KK / 8)) / 256;

  if (ws_size >= needW + needA && (M % BM2) == 0){
    unsigned short* wb = (unsigned short*)d_ws;
    unsigned short* xb = (unsigned short*)((char*)d_ws + needW);
    k_dequant<<<dq_blocks, 256, 0, stream>>>(w, s, wb);
    k_cvtA<<<(M * (KK / 8)) / 256, 256, 0, stream>>>(x, xb);
    const int grid8 = (M / BM2) * (NN / BN2);      // 32*43 = 1376
    k_gemm8c<<<grid8, 512, 0, stream>>>(xb, wb, bias, out);
  } else {
    unsigned short* wb = (unsigned short*)d_ws;
    k_dequant<<<dq_blocks, 256, 0, stream>>>(w, s, wb);
    const int grid = (M / BM) * (NN / BN);
    k_gemm_ws<<<grid, 256, 0, stream>>>(x, wb, bias, out);
  }
}